// Round 5
// baseline (448.330 us; speedup 1.0000x reference)
//
#include <hip/hip_runtime.h>
#include <hip/hip_bf16.h>
#include <math.h>

#define B_ 4
#define N_ 4096
#define F_ 128
#define K_ 32
#define EPS_ 1e-8f

typedef __attribute__((ext_vector_type(8))) __bf16 bf16x8;
typedef __attribute__((ext_vector_type(4))) float f32x4;
typedef __attribute__((ext_vector_type(4))) unsigned int u32x4;

// ws float-index layout
#define WS_SSOFT   0          // 131072
#define WS_SQ      131072     // 4096
#define WS_SSP     135168     // 64 blocks * 1024 = 65536 (ss partials)
#define WS_WFS     200704     // [N/32][2][64] bf16x8 = 256KB
#define WS_WFH     266240     // [B][N/32][2][64] bf16x8 = 1MB
#define WS_OADJP   528384     // 512 gemm blocks * 1024 = 524288
#define WS_NUMDEN  1576960    // 2048
#define WS_PEMB    1579008    // 256 blocks * 4096 = 1048576
#define WS_H       2627584    // B*N ints

// ---- K_pre: fused s_soft softmax + ss partials + gumbel hard-sample + W-fragment build.
__global__ void k_pre(const float* __restrict__ logits, const float* __restrict__ gum,
                      float* __restrict__ s_soft, float* __restrict__ sq,
                      float* __restrict__ ssp, float* __restrict__ s_sample,
                      int* __restrict__ h, bf16x8* __restrict__ wfs,
                      bf16x8* __restrict__ wfh, float t1, float t2) {
  __shared__ float sl[64][33];
  __shared__ int hl[4][64];
  int t = threadIdx.x;
  int r = blockIdx.x;
  int n0 = r * 64;

  if (t < 64) {
    int n = n0 + t;
    float z[32];
    float mx = -1e30f;
    for (int k = 0; k < 32; ++k) { z[k] = logits[n*32+k] / t2; mx = fmaxf(mx, z[k]); }
    float s = 0.f;
    for (int k = 0; k < 32; ++k) { z[k] = expf(z[k]-mx); s += z[k]; }
    float sqa = 0.f;
    for (int k = 0; k < 32; ++k) {
      float v = z[k] / s;
      s_soft[n*32+k] = v;
      sl[t][k] = v;
      sqa += v*v;
    }
    sq[n] = sqa;
  }

  {
    int b = t >> 6, nn = t & 63;
    int n = n0 + nn;
    size_t i = (size_t)b * N_ + n;
    float z[32];
    float mx = -1e30f;
    for (int k = 0; k < 32; ++k) { z[k] = logits[n*32+k]/t1 + gum[i*32+k]; mx = fmaxf(mx, z[k]); }
    float s = 0.f;
    for (int k = 0; k < 32; ++k) { z[k] = expf(z[k]-mx); s += z[k]; }
    int am = 0; float best = -1.f;
    for (int k = 0; k < 32; ++k) { z[k] = z[k]/s; if (z[k] > best) { best = z[k]; am = k; } }
    for (int k = 0; k < 32; ++k) {
      float yh = (k==am) ? 1.f : 0.f;
      s_sample[i*32+k] = (yh - z[k]) + z[k] + EPS_;
    }
    h[i] = am;
    hl[b][nn] = am;
  }
  __syncthreads();

  for (int pp = 0; pp < 4; ++pp) {
    int p = pp*256 + t;
    int k = p >> 5, l = p & 31;
    float a = 0.f;
    for (int rr = 0; rr < 64; ++rr) a += sl[rr][k]*sl[rr][l];
    ssp[(size_t)r*1024 + p] = a;
  }

  {
    int lane = t & 63;
    int c = (t >> 6) & 1;
    int tts = t >> 7;
    int col = c*16 + (lane & 15);
    int lrow = tts*32 + (lane >> 4)*8;
    bf16x8 v;
    #pragma unroll
    for (int j = 0; j < 8; ++j) v[j] = (__bf16)sl[lrow+j][col];
    wfs[((size_t)(2*r + tts)*2 + c)*64 + lane] = v;
  }

  for (int it = 0; it < 4; ++it) {
    int p = it*256 + t;
    int lane = p & 63;
    int c = (p >> 6) & 1;
    int tts = (p >> 7) & 1;
    int b = p >> 8;
    int cc = c*16 + (lane & 15);
    int lrow = tts*32 + (lane >> 4)*8;
    bf16x8 v;
    #pragma unroll
    for (int j = 0; j < 8; ++j) v[j] = (__bf16)((hl[b][lrow+j] == cc) ? 1.f : 0.f);
    wfh[(((size_t)b*(N_/32) + 2*r + tts)*2 + c)*64 + lane] = v;
  }
}

#define NT(p) __builtin_nontemporal_load((const f32x4*)(p))

union PK2 { __bf16 h[2]; unsigned int u; };
union FRU { u32x4 q; bf16x8 v; };

static __device__ __forceinline__ unsigned int pk2(float a, float b) {
  PK2 x; x.h[0] = (__bf16)a; x.h[1] = (__bf16)b; return x.u;
}

// ---- K_gemm: bid<512 = GEMM (32 rows x full K=4096 per block, K-split over 4 waves);
// bid 512..767 = out_emb pooling (dispatched last, fills tail).
// Staging: 32 rows x 256 K fp32 per stage, 1 KB contiguous burst per row (8 thr/row),
// pk2 -> swizzled LDS bf16 tile, ds_read_b128 fragments. Epilogue is linear in C, so
// each wave applies it to its K-partial accumulators directly.
__launch_bounds__(256, 3)
__global__ void k_gemm(const float* __restrict__ adj, const float* __restrict__ emb,
                       const bf16x8* __restrict__ wfs, const bf16x8* __restrict__ wfh,
                       const float* __restrict__ s_soft, const float* __restrict__ sq,
                       const int* __restrict__ h, float* __restrict__ numden_p,
                       float* __restrict__ oadjp, float* __restrict__ pemb) {
  __shared__ u32x4 la[32*32];         // 32 rows x 256 bf16 (swizzled), 16 KB
  __shared__ float oal[1024];
  __shared__ float rn[4], rd[4];
  int t = threadIdx.x;
  int bid = blockIdx.x;

  if (bid >= 512) {
    // ---- out_emb partial pooling (64 rows per block) ----
    __shared__ float accl[4096];
    int ob = bid - 512;
    for (int i = t; i < 4096; i += 256) accl[i] = 0.f;
    __syncthreads();
    int b = ob >> 6;
    int n0 = (ob & 63) * 64;
    int f = t & 127, rr = t >> 7;
    for (int it = 0; it < 32; ++it) {
      int n = n0 + it*2 + rr;
      float v = emb[((size_t)b*N_ + n)*F_ + f];
      int hv = h[b*N_ + n];
      atomicAdd(&accl[hv*128 + f], v);
    }
    __syncthreads();
    for (int i = t; i < 4096; i += 256) pemb[(size_t)ob*4096 + i] = accl[i];
    return;
  }

  int w = t >> 6, l = t & 63;
  int lr = l & 15, lhi = l >> 4;
  int b = bid >> 7, rb = bid & 127;
  int row0 = rb * 32;

  for (int i = t; i < 1024; i += 256) oal[i] = 0.f;

  // staging: thread covers row (t>>3), floats (t&7)*32 .. +32 of each 256-K stage
  int srow = t >> 3;
  const float* pA = adj + (size_t)b*N_*N_ + (size_t)(row0 + srow)*N_ + (t & 7)*32;

  f32x4 acc00 = {0,0,0,0}, acc01 = {0,0,0,0}, acc02 = {0,0,0,0}, acc03 = {0,0,0,0};
  f32x4 acc10 = {0,0,0,0}, acc11 = {0,0,0,0}, acc12 = {0,0,0,0}, acc13 = {0,0,0,0};

  f32x4 ar[2][8];
  // prologue: stage 0 loads
  #pragma unroll
  for (int i = 0; i < 8; ++i) ar[0][i] = NT(pA + i*4);

  // unroll 2 so cur = s&1 is compile-time (keeps ar[] in registers, not scratch)
  #pragma unroll 2
  for (int s = 0; s < 16; ++s) {
    int cur = s & 1;
    if (s < 15) {
      #pragma unroll
      for (int i = 0; i < 8; ++i) ar[cur^1][i] = NT(pA + (s+1)*256 + i*4);
    }
    if (s > 0) __syncthreads();          // all waves done reading previous stage
    // pk2 + swizzled ds_write (4 x b128 per thread)
    {
      int gbase = srow*32 + (t & 7)*4;
      int swz = srow & 7;
      #pragma unroll
      for (int q = 0; q < 4; ++q) {
        u32x4 val;
        #pragma unroll
        for (int m = 0; m < 4; ++m) {
          int j = q*4 + m;                // u32 index within 16
          val[m] = pk2(ar[cur][j>>1][(j&1)*2], ar[cur][j>>1][(j&1)*2+1]);
        }
        la[(gbase + q) ^ swz] = val;
      }
    }
    __syncthreads();
    // compute: wave w handles K-cols [w*64, w*64+64) of this stage = 2 K-steps
    #pragma unroll
    for (int st = 0; st < 2; ++st) {
      int c32 = s*8 + w*2 + st;
      bf16x8 wf0 = wfs[((size_t)c32*2 + 0)*64 + l];
      bf16x8 wf1 = wfs[((size_t)c32*2 + 1)*64 + l];
      bf16x8 wh0 = wfh[(((size_t)b*(N_/32) + c32)*2 + 0)*64 + l];
      bf16x8 wh1 = wfh[(((size_t)b*(N_/32) + c32)*2 + 1)*64 + l];
      FRU fa0, fa1;
      {
        int row = lr;                    // rt = 0
        fa0.q = la[(row*32 + w*8 + st*4 + lhi) ^ (row & 7)];
        row = 16 + lr;                   // rt = 1
        fa1.q = la[(row*32 + w*8 + st*4 + lhi) ^ (row & 7)];
      }
      acc00 = __builtin_amdgcn_mfma_f32_16x16x32_bf16(fa0.v, wf0, acc00, 0, 0, 0);
      acc01 = __builtin_amdgcn_mfma_f32_16x16x32_bf16(fa0.v, wf1, acc01, 0, 0, 0);
      acc02 = __builtin_amdgcn_mfma_f32_16x16x32_bf16(fa0.v, wh0, acc02, 0, 0, 0);
      acc03 = __builtin_amdgcn_mfma_f32_16x16x32_bf16(fa0.v, wh1, acc03, 0, 0, 0);
      acc10 = __builtin_amdgcn_mfma_f32_16x16x32_bf16(fa1.v, wf0, acc10, 0, 0, 0);
      acc11 = __builtin_amdgcn_mfma_f32_16x16x32_bf16(fa1.v, wf1, acc11, 0, 0, 0);
      acc12 = __builtin_amdgcn_mfma_f32_16x16x32_bf16(fa1.v, wh0, acc12, 0, 0, 0);
      acc13 = __builtin_amdgcn_mfma_f32_16x16x32_bf16(fa1.v, wh1, acc13, 0, 0, 0);
    }
  }

  // epilogue: each wave's acc is a K-partial over the SAME rows row0..row0+31.
  // Everything below is linear in C, so partials sum correctly via atomics/rn/rd.
  float numacc = 0.f, denacc = 0.f;
  {
    f32x4 a0s[2] = {acc00, acc10}, a1s[2] = {acc01, acc11};
    f32x4 a2s[2] = {acc02, acc12}, a3s[2] = {acc03, acc13};
    #pragma unroll
    for (int rt = 0; rt < 2; ++rt) {
      int rbase = row0 + rt*16 + lhi*4;
      #pragma unroll
      for (int i = 0; i < 4; ++i) {
        int row = rbase + i;
        float sqv = sq[row];
        int hv = h[b*N_ + row];
        numacc += a0s[rt][i] * s_soft[row*32 + lr];
        numacc += a1s[rt][i] * s_soft[row*32 + 16 + lr];
        float v2 = a2s[rt][i], v3 = a3s[rt][i];
        denacc += (v2 + v3) * sqv;
        atomicAdd(&oal[hv*32 + lr], v2);
        atomicAdd(&oal[hv*32 + 16 + lr], v3);
      }
    }
  }
  for (int off = 32; off; off >>= 1) {
    numacc += __shfl_down(numacc, off);
    denacc += __shfl_down(denacc, off);
  }
  if (l == 0) { rn[w] = numacc; rd[w] = denacc; }
  __syncthreads();
  if (t == 0) {
    numden_p[bid] = rn[0]+rn[1]+rn[2]+rn[3];
    numden_p[1024 + bid] = rd[0]+rd[1]+rd[2]+rd[3];
  }
  for (int i = t; i < 1024; i += 256) oadjp[(size_t)bid*1024 + i] = oal[i];
}

// ---- K_post: blocks 0..63 reduce out_emb; 64..67 finalize out_adj per batch;
// block 68 computes mincut + ortho scalars. ----
__global__ void k_post(const float* __restrict__ oadjp, const float* __restrict__ pemb,
                       const float* __restrict__ ndp, const float* __restrict__ ssp,
                       float* __restrict__ dout) {
  int blk = blockIdx.x;
  int t = threadIdx.x;
  if (blk < 64) {
    int i = blk*256 + t;                // [0,16384)
    int b = i >> 12, ii = i & 4095;
    float s = 0.f;
    const float* p = pemb + (size_t)(b*64)*4096 + ii;
    for (int j = 0; j < 64; ++j) s += p[(size_t)j*4096];
    dout[i] = s;
  } else if (blk < 68) {
    __shared__ float oal[1024];
    __shared__ float dsh[32];
    int b = blk - 64;
    float a0 = 0.f, a1 = 0.f, a2 = 0.f, a3 = 0.f;
    const float* p = oadjp + (size_t)b*128*1024 + t;
    for (int j = 0; j < 128; ++j) {
      a0 += p[0]; a1 += p[256]; a2 += p[512]; a3 += p[768];
      p += 1024;
    }
    oal[t] = a0; oal[t+256] = a1; oal[t+512] = a2; oal[t+768] = a3;
    __syncthreads();
    if (t < 32) {
      float s = 0.f;
      for (int l = 0; l < 32; ++l) if (l != t) s += oal[t*32+l];
      dsh[t] = sqrtf(s) + EPS_;
    }
    __syncthreads();
    for (int i = t; i < 1024; i += 256) {
      int k = i >> 5, l = i & 31;
      float v = (k == l) ? 0.f : oal[i] / (dsh[k] * dsh[l]);
      dout[16384 + b*1024 + i] = v;
    }
  } else {
    __shared__ float red[256];
    __shared__ float nd[8];
    if (t < 8) {
      int b = t & 3;
      const float* p = ndp + (t >> 2)*1024 + b*128;
      float s = 0.f;
      for (int j = 0; j < 128; ++j) s += p[j];
      nd[t] = s;
    }
    float v0 = 0.f, v1 = 0.f, v2 = 0.f, v3 = 0.f;
    for (int r = 0; r < 64; ++r) {
      const float* p = ssp + (size_t)r*1024 + t;
      v0 += p[0]; v1 += p[256]; v2 += p[512]; v3 += p[768];
    }
    float a = v0*v0 + v1*v1 + v2*v2 + v3*v3;
    red[t] = a; __syncthreads();
    for (int s2 = 128; s2; s2 >>= 1) { if (t < s2) red[t] += red[t+s2]; __syncthreads(); }
    float fro = sqrtf(red[0]);
    __syncthreads();
    float inv = 1.f / fro;
    float dk = (float)(1.0 / sqrt(32.0));
    float c = 0.f;
    {
      float w;
      int p0 = t, p1 = t+256, p2 = t+512, p3 = t+768;
      w = v0*inv - (((p0>>5)==(p0&31)) ? dk : 0.f); c += w*w;
      w = v1*inv - (((p1>>5)==(p1&31)) ? dk : 0.f); c += w*w;
      w = v2*inv - (((p2>>5)==(p2&31)) ? dk : 0.f); c += w*w;
      w = v3*inv - (((p3>>5)==(p3&31)) ? dk : 0.f); c += w*w;
    }
    red[t] = c; __syncthreads();
    for (int s2 = 128; s2; s2 >>= 1) { if (t < s2) red[t] += red[t+s2]; __syncthreads(); }
    if (t == 0) {
      dout[544769] = sqrtf(red[0]);
      float s = 0.f;
      for (int b = 0; b < 4; ++b) s += nd[b] / nd[4+b];
      dout[544768] = -s*0.25f;
    }
  }
}

extern "C" void kernel_launch(void* const* d_in, const int* in_sizes, int n_in,
                              void* d_out, int out_size, void* d_ws, size_t ws_size,
                              hipStream_t stream) {
  const float* emb    = (const float*)d_in[0];
  const float* adj    = (const float*)d_in[1];
  const float* logits = (const float*)d_in[2];
  const float* gum    = (const float*)d_in[3];
  float* out = (float*)d_out;
  float* ws  = (float*)d_ws;

  float t1 = 0.99995f;
  float t2 = (float)(0.99995 * 0.99995);

  float* s_soft = ws + WS_SSOFT;
  float* sq     = ws + WS_SQ;
  float* ssp    = ws + WS_SSP;
  bf16x8* wfs   = (bf16x8*)(ws + WS_WFS);
  bf16x8* wfh   = (bf16x8*)(ws + WS_WFH);
  float* oadjp  = ws + WS_OADJP;
  float* ndp    = ws + WS_NUMDEN;
  float* pemb   = ws + WS_PEMB;
  int* hbuf     = (int*)(ws + WS_H);

  k_pre  <<<64, 256, 0, stream>>>(logits, gum, s_soft, sq, ssp, out + 20480, hbuf, wfs, wfh, t1, t2);
  k_gemm <<<768, 256, 0, stream>>>(adj, emb, wfs, wfh, s_soft, sq, hbuf, ndp, oadjp, pemb);
  k_post <<<69, 256, 0, stream>>>(oadjp, pemb, ndp, ssp, out);
}

// Round 6
// 419.082 us; speedup vs baseline: 1.0698x; 1.0698x over previous
//
#include <hip/hip_runtime.h>
#include <hip/hip_bf16.h>
#include <math.h>

#define B_ 4
#define N_ 4096
#define F_ 128
#define K_ 32
#define EPS_ 1e-8f

typedef __attribute__((ext_vector_type(8))) __bf16 bf16x8;
typedef __attribute__((ext_vector_type(4))) float f32x4;

// ws float-index layout
#define WS_SSOFT   0          // 131072
#define WS_SQ      131072     // 4096
#define WS_SSP     135168     // 64 blocks * 1024 = 65536 (ss partials)
#define WS_WFS     200704     // [N/32][2][64] bf16x8 = 256KB
#define WS_WFH     266240     // [B][N/32][2][64] bf16x8 = 1MB
#define WS_OADJP   528384     // 1024 gemm blocks * 1024 = 1048576
#define WS_NUMDEN  1576960    // 2048
#define WS_PEMB    1579008    // 1024 blocks * 4096 = 4194304
#define WS_H       5773312    // B*N ints

// ---- K_pre: fused s_soft softmax + ss partials + gumbel hard-sample + W-fragment build.
__global__ void k_pre(const float* __restrict__ logits, const float* __restrict__ gum,
                      float* __restrict__ s_soft, float* __restrict__ sq,
                      float* __restrict__ ssp, float* __restrict__ s_sample,
                      int* __restrict__ h, bf16x8* __restrict__ wfs,
                      bf16x8* __restrict__ wfh, float t1, float t2) {
  __shared__ float sl[64][33];
  __shared__ int hl[4][64];
  int t = threadIdx.x;
  int r = blockIdx.x;
  int n0 = r * 64;

  if (t < 64) {
    int n = n0 + t;
    float z[32];
    float mx = -1e30f;
    for (int k = 0; k < 32; ++k) { z[k] = logits[n*32+k] / t2; mx = fmaxf(mx, z[k]); }
    float s = 0.f;
    for (int k = 0; k < 32; ++k) { z[k] = expf(z[k]-mx); s += z[k]; }
    float sqa = 0.f;
    for (int k = 0; k < 32; ++k) {
      float v = z[k] / s;
      s_soft[n*32+k] = v;
      sl[t][k] = v;
      sqa += v*v;
    }
    sq[n] = sqa;
  }

  {
    int b = t >> 6, nn = t & 63;
    int n = n0 + nn;
    size_t i = (size_t)b * N_ + n;
    float z[32];
    float mx = -1e30f;
    for (int k = 0; k < 32; ++k) { z[k] = logits[n*32+k]/t1 + gum[i*32+k]; mx = fmaxf(mx, z[k]); }
    float s = 0.f;
    for (int k = 0; k < 32; ++k) { z[k] = expf(z[k]-mx); s += z[k]; }
    int am = 0; float best = -1.f;
    for (int k = 0; k < 32; ++k) { z[k] = z[k]/s; if (z[k] > best) { best = z[k]; am = k; } }
    for (int k = 0; k < 32; ++k) {
      float yh = (k==am) ? 1.f : 0.f;
      s_sample[i*32+k] = (yh - z[k]) + z[k] + EPS_;
    }
    h[i] = am;
    hl[b][nn] = am;
  }
  __syncthreads();

  for (int pp = 0; pp < 4; ++pp) {
    int p = pp*256 + t;
    int k = p >> 5, l = p & 31;
    float a = 0.f;
    for (int rr = 0; rr < 64; ++rr) a += sl[rr][k]*sl[rr][l];
    ssp[(size_t)r*1024 + p] = a;
  }

  {
    int lane = t & 63;
    int c = (t >> 6) & 1;
    int tts = t >> 7;
    int col = c*16 + (lane & 15);
    int lrow = tts*32 + (lane >> 4)*8;
    bf16x8 v;
    #pragma unroll
    for (int j = 0; j < 8; ++j) v[j] = (__bf16)sl[lrow+j][col];
    wfs[((size_t)(2*r + tts)*2 + c)*64 + lane] = v;
  }

  for (int it = 0; it < 4; ++it) {
    int p = it*256 + t;
    int lane = p & 63;
    int c = (p >> 6) & 1;
    int tts = (p >> 7) & 1;
    int b = p >> 8;
    int cc = c*16 + (lane & 15);
    int lrow = tts*32 + (lane >> 4)*8;
    bf16x8 v;
    #pragma unroll
    for (int j = 0; j < 8; ++j) v[j] = (__bf16)((hl[b][lrow+j] == cc) ? 1.f : 0.f);
    wfh[(((size_t)b*(N_/32) + 2*r + tts)*2 + c)*64 + lane] = v;
  }
}

#define NT(p) __builtin_nontemporal_load((const f32x4*)(p))

// ---- K_gemm: 1024 blocks = B * 32 rowblocks * 8 splitm (exactly 4/CU, single
// generation, no tail). Each block: (a) pools its 16-row emb slice into pemb[bid]
// (tail-generation removal vs separate outemb blocks), (b) runs the direct-load
// 128x512 GEMM chunk (no K-loop barriers), (c) fused epilogue.
__launch_bounds__(256, 4)
__global__ void k_gemm(const float* __restrict__ adj, const float* __restrict__ emb,
                       const bf16x8* __restrict__ wfs, const bf16x8* __restrict__ wfh,
                       const float* __restrict__ s_soft, const float* __restrict__ sq,
                       const int* __restrict__ h, float* __restrict__ numden_p,
                       float* __restrict__ oadjp, float* __restrict__ pemb) {
  __shared__ float sh[4096];
  __shared__ float rn[4], rd[4];
  int t = threadIdx.x;
  int bid = blockIdx.x;
  int w = t >> 6, l = t & 63;
  int lr = l & 15, lhi = l >> 4;
  int sp = bid & 7, r = (bid >> 3) & 31, b = bid >> 8;
  int row0 = r*128;
  int m0 = sp*512;

  // ---- phase A: emb pooling for rows [row0 + sp*16, +16) of batch b ----
  for (int i = t; i < 4096; i += 256) sh[i] = 0.f;
  __syncthreads();
  {
    int n0 = row0 + sp*16;
    int f = t & 127, rr2 = t >> 7;
    for (int it = 0; it < 8; ++it) {
      int n = n0 + it*2 + rr2;
      float v = emb[((size_t)b*N_ + n)*F_ + f];
      int hv = h[b*N_ + n];
      atomicAdd(&sh[hv*128 + f], v);
    }
  }
  __syncthreads();
  for (int i = t; i < 4096; i += 256) pemb[(size_t)bid*4096 + i] = sh[i];
  __syncthreads();
  for (int i = t; i < 1024; i += 256) sh[i] = 0.f;    // oal region
  __syncthreads();
  float* oal = sh;

  // ---- phase B: GEMM, direct per-lane A-fragment loads (no LDS, no barriers) ----
  int rowA = row0 + w*32 + lr;          // rt=0 row for this lane

  const float* pA0 = adj + (size_t)b*N_*N_ + (size_t)rowA*N_ + m0 + lhi*8;
  const float* pA1 = pA0 + (size_t)16*N_;
  const bf16x8* pws = wfs + (size_t)(m0 >> 5)*128 + l;
  const bf16x8* pwh = wfh + ((size_t)b*(N_/32) + (m0 >> 5))*128 + l;

  f32x4 acc00 = {0,0,0,0}, acc01 = {0,0,0,0}, acc02 = {0,0,0,0}, acc03 = {0,0,0,0};
  f32x4 acc10 = {0,0,0,0}, acc11 = {0,0,0,0}, acc12 = {0,0,0,0}, acc13 = {0,0,0,0};

  // prime chunk 0
  f32x4 a0lo = NT(pA0), a0hi = NT(pA0 + 4);
  f32x4 a1lo = NT(pA1), a1hi = NT(pA1 + 4);
  bf16x8 wc0 = pws[0], wc1 = pws[64], wc2 = pwh[0], wc3 = pwh[64];

  #pragma unroll 1
  for (int c = 0; c < 16; ++c) {
    f32x4 n0lo, n0hi, n1lo, n1hi;
    bf16x8 wn0, wn1, wn2, wn3;
    if (c < 15) {
      pA0 += 32; pA1 += 32; pws += 128; pwh += 128;
      n0lo = NT(pA0); n0hi = NT(pA0 + 4);
      n1lo = NT(pA1); n1hi = NT(pA1 + 4);
      wn0 = pws[0]; wn1 = pws[64]; wn2 = pwh[0]; wn3 = pwh[64];
    }
    bf16x8 fa0, fa1;
    #pragma unroll
    for (int j = 0; j < 4; ++j) {
      fa0[j]   = (__bf16)a0lo[j];
      fa0[j+4] = (__bf16)a0hi[j];
      fa1[j]   = (__bf16)a1lo[j];
      fa1[j+4] = (__bf16)a1hi[j];
    }
    acc00 = __builtin_amdgcn_mfma_f32_16x16x32_bf16(fa0, wc0, acc00, 0, 0, 0);
    acc01 = __builtin_amdgcn_mfma_f32_16x16x32_bf16(fa0, wc1, acc01, 0, 0, 0);
    acc02 = __builtin_amdgcn_mfma_f32_16x16x32_bf16(fa0, wc2, acc02, 0, 0, 0);
    acc03 = __builtin_amdgcn_mfma_f32_16x16x32_bf16(fa0, wc3, acc03, 0, 0, 0);
    acc10 = __builtin_amdgcn_mfma_f32_16x16x32_bf16(fa1, wc0, acc10, 0, 0, 0);
    acc11 = __builtin_amdgcn_mfma_f32_16x16x32_bf16(fa1, wc1, acc11, 0, 0, 0);
    acc12 = __builtin_amdgcn_mfma_f32_16x16x32_bf16(fa1, wc2, acc12, 0, 0, 0);
    acc13 = __builtin_amdgcn_mfma_f32_16x16x32_bf16(fa1, wc3, acc13, 0, 0, 0);
    if (c < 15) {
      a0lo = n0lo; a0hi = n0hi; a1lo = n1lo; a1hi = n1hi;
      wc0 = wn0; wc1 = wn1; wc2 = wn2; wc3 = wn3;
    }
  }

  // epilogue: C-frag lane l holds col = c*16 + (l&15), rows row0 + w*32 + rt*16 + (l>>4)*4 + i
  float numacc = 0.f, denacc = 0.f;
  {
    f32x4 a0s[2] = {acc00, acc10}, a1s[2] = {acc01, acc11};
    f32x4 a2s[2] = {acc02, acc12}, a3s[2] = {acc03, acc13};
    int wrow0 = row0 + w*32;
    #pragma unroll
    for (int rt = 0; rt < 2; ++rt) {
      int rbase = wrow0 + rt*16 + lhi*4;
      #pragma unroll
      for (int i = 0; i < 4; ++i) {
        int row = rbase + i;
        float sqv = sq[row];
        int hv = h[b*N_ + row];
        numacc += a0s[rt][i] * s_soft[row*32 + lr];
        numacc += a1s[rt][i] * s_soft[row*32 + 16 + lr];
        float v2 = a2s[rt][i], v3 = a3s[rt][i];
        denacc += (v2 + v3) * sqv;
        atomicAdd(&oal[hv*32 + lr], v2);
        atomicAdd(&oal[hv*32 + 16 + lr], v3);
      }
    }
  }
  for (int off = 32; off; off >>= 1) {
    numacc += __shfl_down(numacc, off);
    denacc += __shfl_down(denacc, off);
  }
  if (l == 0) { rn[w] = numacc; rd[w] = denacc; }
  __syncthreads();
  if (t == 0) {
    numden_p[bid] = rn[0]+rn[1]+rn[2]+rn[3];
    numden_p[1024 + bid] = rd[0]+rd[1]+rd[2]+rd[3];
  }
  for (int i = t; i < 1024; i += 256) oadjp[(size_t)bid*1024 + i] = oal[i];
}

// ---- K_post: blocks 0..63 reduce out_emb (256 partials/batch); 64..67 finalize
// out_adj per batch; block 68 computes mincut + ortho scalars. ----
__global__ void k_post(const float* __restrict__ oadjp, const float* __restrict__ pemb,
                       const float* __restrict__ ndp, const float* __restrict__ ssp,
                       float* __restrict__ dout) {
  int blk = blockIdx.x;
  int t = threadIdx.x;
  if (blk < 64) {
    int i = blk*256 + t;                // [0,16384)
    int b = i >> 12, ii = i & 4095;
    float s = 0.f;
    const float* p = pemb + (size_t)(b*256)*4096 + ii;
    for (int j = 0; j < 256; ++j) s += p[(size_t)j*4096];
    dout[i] = s;
  } else if (blk < 68) {
    __shared__ float oal[1024];
    __shared__ float dsh[32];
    int b = blk - 64;
    float a0 = 0.f, a1 = 0.f, a2 = 0.f, a3 = 0.f;
    const float* p = oadjp + (size_t)b*256*1024 + t;
    for (int j = 0; j < 256; ++j) {
      a0 += p[0]; a1 += p[256]; a2 += p[512]; a3 += p[768];
      p += 1024;
    }
    oal[t] = a0; oal[t+256] = a1; oal[t+512] = a2; oal[t+768] = a3;
    __syncthreads();
    if (t < 32) {
      float s = 0.f;
      for (int l = 0; l < 32; ++l) if (l != t) s += oal[t*32+l];
      dsh[t] = sqrtf(s) + EPS_;
    }
    __syncthreads();
    for (int i = t; i < 1024; i += 256) {
      int k = i >> 5, l = i & 31;
      float v = (k == l) ? 0.f : oal[i] / (dsh[k] * dsh[l]);
      dout[16384 + b*1024 + i] = v;
    }
  } else {
    __shared__ float red[256];
    __shared__ float nd[8];
    if (t < 8) {
      int b = t & 3;
      const float* p = ndp + (t >> 2)*1024 + b*256;
      float s = 0.f;
      for (int j = 0; j < 256; ++j) s += p[j];
      nd[t] = s;
    }
    float v0 = 0.f, v1 = 0.f, v2 = 0.f, v3 = 0.f;
    for (int r = 0; r < 64; ++r) {
      const float* p = ssp + (size_t)r*1024 + t;
      v0 += p[0]; v1 += p[256]; v2 += p[512]; v3 += p[768];
    }
    float a = v0*v0 + v1*v1 + v2*v2 + v3*v3;
    red[t] = a; __syncthreads();
    for (int s2 = 128; s2; s2 >>= 1) { if (t < s2) red[t] += red[t+s2]; __syncthreads(); }
    float fro = sqrtf(red[0]);
    __syncthreads();
    float inv = 1.f / fro;
    float dk = (float)(1.0 / sqrt(32.0));
    float c = 0.f;
    {
      float w;
      int p0 = t, p1 = t+256, p2 = t+512, p3 = t+768;
      w = v0*inv - (((p0>>5)==(p0&31)) ? dk : 0.f); c += w*w;
      w = v1*inv - (((p1>>5)==(p1&31)) ? dk : 0.f); c += w*w;
      w = v2*inv - (((p2>>5)==(p2&31)) ? dk : 0.f); c += w*w;
      w = v3*inv - (((p3>>5)==(p3&31)) ? dk : 0.f); c += w*w;
    }
    red[t] = c; __syncthreads();
    for (int s2 = 128; s2; s2 >>= 1) { if (t < s2) red[t] += red[t+s2]; __syncthreads(); }
    if (t == 0) {
      dout[544769] = sqrtf(red[0]);
      float s = 0.f;
      for (int b = 0; b < 4; ++b) s += nd[b] / nd[4+b];
      dout[544768] = -s*0.25f;
    }
  }
}

extern "C" void kernel_launch(void* const* d_in, const int* in_sizes, int n_in,
                              void* d_out, int out_size, void* d_ws, size_t ws_size,
                              hipStream_t stream) {
  const float* emb    = (const float*)d_in[0];
  const float* adj    = (const float*)d_in[1];
  const float* logits = (const float*)d_in[2];
  const float* gum    = (const float*)d_in[3];
  float* out = (float*)d_out;
  float* ws  = (float*)d_ws;

  float t1 = 0.99995f;
  float t2 = (float)(0.99995 * 0.99995);

  float* s_soft = ws + WS_SSOFT;
  float* sq     = ws + WS_SQ;
  float* ssp    = ws + WS_SSP;
  bf16x8* wfs   = (bf16x8*)(ws + WS_WFS);
  bf16x8* wfh   = (bf16x8*)(ws + WS_WFH);
  float* oadjp  = ws + WS_OADJP;
  float* ndp    = ws + WS_NUMDEN;
  float* pemb   = ws + WS_PEMB;
  int* hbuf     = (int*)(ws + WS_H);

  k_pre  <<<64, 256, 0, stream>>>(logits, gum, s_soft, sq, ssp, out + 20480, hbuf, wfs, wfh, t1, t2);
  k_gemm <<<1024, 256, 0, stream>>>(adj, emb, wfs, wfh, s_soft, sq, hbuf, ndp, oadjp, pemb);
  k_post <<<69, 256, 0, stream>>>(oadjp, pemb, ndp, ssp, out);
}